// Round 12
// baseline (238.547 us; speedup 1.0000x reference)
//
#include <hip/hip_runtime.h>

typedef short bf16x8 __attribute__((ext_vector_type(8)));
typedef float f32x16 __attribute__((ext_vector_type(16)));
typedef int   i32x4  __attribute__((ext_vector_type(4)));

#define INV_SQRT165 0.07784989441615349f
#define FINAL_SCALE 0.0032113081446662823f   /* sqrt(165)/4000 */
#define ZERO16 ((f32x16){0.f,0.f,0.f,0.f,0.f,0.f,0.f,0.f,0.f,0.f,0.f,0.f,0.f,0.f,0.f,0.f})

__device__ __forceinline__ unsigned short f2bf(float f) {
  unsigned int u = __builtin_bit_cast(unsigned int, f);
  unsigned int r = (u + 0x7FFFu + ((u >> 16) & 1u)) >> 16;
  return (unsigned short)r;
}
__device__ __forceinline__ float bf2f(unsigned short h) {
  unsigned int u = ((unsigned int)h) << 16;
  return __builtin_bit_cast(float, u);
}
// fast pack: round-half-up (2 ops/value); inputs are relu'd (>=0)
__device__ __forceinline__ unsigned int pack_bf2f(float lo, float hi) {
  unsigned int a = (__builtin_bit_cast(unsigned int, lo) + 0x8000u) >> 16;
  unsigned int b = (__builtin_bit_cast(unsigned int, hi) + 0x8000u) & 0xFFFF0000u;
  return b | a;
}

__device__ __forceinline__ void gl_lds16(const void* g, void* l) {
  __builtin_amdgcn_global_load_lds(
      (const __attribute__((address_space(1))) unsigned int*)(unsigned long long)g,
      (__attribute__((address_space(3))) unsigned int*)(unsigned int)(unsigned long long)l,
      16, 0, 0);
}

__device__ __forceinline__ void decode_i(int i, int& lv, int& rel) {
  if (i < 1)       { lv = 0; rel = i; }
  else if (i < 10) { lv = 1; rel = i - 1; }
  else if (i < 35) { lv = 2; rel = i - 10; }
  else if (i < 84) { lv = 3; rel = i - 35; }
  else             { lv = 4; rel = i - 84; }
}
__device__ __forceinline__ int divq(int rel, int lv) {   // rel / (2lv+1), rel < 81
  const int mag[5] = {32768, 10923, 6554, 4682, 3641};
  return (rel * mag[lv]) >> 15;
}

// E-row permutation: row p holds actual g = G(p) so GEMM1's C/D register order IS
// GEMM2's A-frag k-slot order (no cross-lane exchange).
__device__ __forceinline__ int gperm(int p) {
  int a = p & 3, hlp = (p >> 2) & 1, c = p >> 3;
  return ((c >> 1) << 4) + hlp * 8 + ((c & 1) << 2) + a;
}

// ---------------- prep ----------------
// blocks 0..511: (ci = bx>>2, yg = bx&3) Da chunk -> E-fold for 4 y; yg==0 also d2pre.
// blocks 512..583: ewpre. blocks 584..594: psi2.
__global__ __launch_bounds__(256) void prep_k(const float* __restrict__ Da,
                                              const float* __restrict__ ew,
                                              const float* __restrict__ Y,
                                              const float* __restrict__ w_s2,
                                              const float* __restrict__ Dk,
                                              const float* __restrict__ w_so3,
                                              unsigned short* __restrict__ e1pre,
                                              unsigned short* __restrict__ d2pre,
                                              unsigned short* __restrict__ ewpre,
                                              float* __restrict__ psi2) {
  __shared__ __align__(16) unsigned short lds[13824];
  const int tid = threadIdx.x;
  const int l = tid & 63, hl = l >> 5, ln = l & 31;
  if (blockIdx.x < 512) {
    const int ci = blockIdx.x >> 2, yg = blockIdx.x & 3;
    const int g0 = ci * 32;
    float* psi1L = (float*)(lds + 6464);
    for (int e = tid; e < 6400; e += 256) lds[e] = 0;
    for (int e = tid; e < 400; e += 256) {
      int yv = e / 25, iv = e % 25;
      float s = 0.f;
      for (int n = 0; n < 48; n++) s += Y[n * 25 + iv] * w_s2[yv * 48 + n];
      psi1L[e] = s * 0.14433756729740643f;
    }
    __syncthreads();
    int rows = 4000 - g0; if (rows > 32) rows = 32; if (rows < 0) rows = 0;
    int ne = rows * 165;
    for (int e = tid; e < ne; e += 256) {
      int gl_ = e / 165, k = e - gl_ * 165;
      lds[gl_ * 200 + k] = f2bf(Da[g0 * 165 + e]);
    }
    __syncthreads();
    if (yg == 0) {
#pragma unroll
      for (int it = 0; it < 3; it++) {
        int tt = it * 4 + (tid >> 6);
        int nf = tt >> 1, gk = tt & 1;
        unsigned short v[8];
#pragma unroll
        for (int j = 0; j < 8; j++)
          v[j] = lds[(gk * 16 + hl * 8 + j) * 200 + nf * 32 + ln];
        *(i32x4*)(d2pre + ci * 6144 + tt * 512 + l * 8) = *(i32x4*)v;
      }
    }
    for (int yi = 0; yi < 4; yi++) {
      int yy = yg * 4 + yi;
#pragma unroll
      for (int it = 0; it < 4; it++) {
        int idx = it * 256 + tid;
        int kf = idx >> 9, r2 = idx & 511;
        int ll = r2 >> 3, j = r2 & 7;
        int lnn = ll & 31, hll = ll >> 5;
        int k = kf * 16 + hll * 8 + j;
        unsigned short ov = 0;
        if (k < 25) {
          int lv = (k < 1) ? 0 : (k < 4) ? 1 : (k < 9) ? 2 : (k < 16) ? 3 : 4;
          int d = 2 * lv + 1;
          int m = k - lv * lv;
          int off165 = lv * (4 * lv * lv - 1) / 3;   // {0,1,10,35,84}
          int gp = gperm(lnn);
          float s = 0.f;
          const float* pr = psi1L + yy * 25 + lv * lv;
          const unsigned short* dr = lds + gp * 200 + off165 + m;
          for (int j2 = 0; j2 < d; j2++) s += pr[j2] * bf2f(dr[j2 * d]);
          ov = f2bf(s * INV_SQRT165);
        }
        e1pre[((yy * 128 + ci) * 2 + kf) * 512 + ll * 8 + j] = ov;
      }
    }
  } else if (blockIdx.x < 584) {
    const int bx2 = blockIdx.x - 512;
    const int n0 = bx2 * 64;
    for (int e = tid; e < 13824; e += 256) lds[e] = 0;
    __syncthreads();
    for (int e = tid; e < 10560; e += 256) {
      int k = e >> 6, n = e & 63;
      lds[k * 72 + n] = f2bf(ew[k * 4608 + n0 + n]);
    }
    __syncthreads();
#pragma unroll
    for (int it = 0; it < 6; it++) {
      int tb = it * 4 + (tid >> 6);
      int nt2 = tb / 12, kf = tb - nt2 * 12;
      unsigned short v[8];
#pragma unroll
      for (int j = 0; j < 8; j++)
        v[j] = lds[(kf * 16 + hl * 8 + j) * 72 + nt2 * 32 + ln];
      *(i32x4*)(ewpre + (bx2 * 2 + nt2) * 6144 + kf * 512 + l * 8) = *(i32x4*)v;
    }
  } else {
    int t = (blockIdx.x - 584) * 256 + tid;
    if (t < 2640) {
      int ch = t / 165, i = t % 165;
      float s = 0.f;
      for (int n = 0; n < 192; n++) s += Dk[n * 165 + i] * w_so3[ch * 192 + n];
      psi2[t] = s * (0.07216878364870323f * FINAL_SCALE);
    }
  }
}

// ---------------- fused MLP: permuted-E, wave = 32b x 96n, 4 blocks/CU ----------------
// Grid 1024: h = bx&1 (g-half), y = (bx>>1)&15, btg = bx>>5 (0..31, 64 b rows/block).
// Wave w: bw = w>>1 (m-tile), ng = w&1 (n-half). GEMM1 duplicated per n-half (cheap,
// no cross-wave sync); per wave per chunk: 2 E reads + 2 GEMM1 + 8-dword pack +
// 6 B reads + 6 GEMM2. 14KB dbuf (28KB LDS) -> 4 blocks/CU = 4 barrier domains.
__global__ __launch_bounds__(256, 4) void fused_mlp_k(
    const float* __restrict__ x,
    const unsigned short* __restrict__ e1pre,
    const unsigned short* __restrict__ d2pre,
    unsigned short* __restrict__ part)
{
  __shared__ __align__(16) unsigned char smem[28672];   // 2 x 14KB (12KB d2 + 2KB E)
  const int tid = threadIdx.x;
  const int w = tid >> 6, l = tid & 63;
  const int hl = l >> 5, ln = l & 31;
  const int h = blockIdx.x & 1;
  const int y = (blockIdx.x >> 1) & 15;
  const int btg = blockIdx.x >> 5;
  const int bw = w >> 1, ng = w & 1;
  const int bt = btg * 2 + bw;                   // m-tile (32 b rows)
  const int c0 = h * 64;

  // x fragments (B-operand of GEMM1): lane ln -> batch b = bt*32+ln, k pad to 32
  bf16x8 xf[2];
  {
    const float* xr = x + (bt * 32 + ln) * 25;
#pragma unroll
    for (int kf = 0; kf < 2; kf++) {
      unsigned short v[8];
#pragma unroll
      for (int j = 0; j < 8; j++) {
        int k = kf * 16 + hl * 8 + j;
        v[j] = (k < 25) ? f2bf(xr[k]) : (unsigned short)0;
      }
      xf[kf] = *(bf16x8*)v;
    }
  }

  f32x16 o[3];
#pragma unroll
  for (int i = 0; i < 3; i++) o[i] = ZERO16;

  const unsigned short* ebase = e1pre + (y * 128) * 1024;

  // prologue: stage chunk c0 -> buffer 0 (14 x 1KB; waves take 4,4,4,2)
#pragma unroll
  for (int i = 0; i < 4; i++) {
    int tb = w * 4 + i;
    if (tb < 14) {
      const unsigned short* g = (tb < 12) ? (d2pre + c0 * 6144 + tb * 512 + l * 8)
                                          : (ebase + (c0 * 2 + (tb - 12)) * 512 + l * 8);
      gl_lds16(g, smem + tb * 1024);
    }
  }

  for (int ci = 0; ci < 64; ci++) {
    __syncthreads();
    const unsigned char* cb = smem + (ci & 1) * 14336;
    if (ci < 63) {
      unsigned char* nb = smem + ((ci + 1) & 1) * 14336;
      const int c = c0 + ci + 1;
#pragma unroll
      for (int i = 0; i < 4; i++) {
        int tb = w * 4 + i;
        if (tb < 14) {
          const unsigned short* g = (tb < 12) ? (d2pre + c * 6144 + tb * 512 + l * 8)
                                              : (ebase + (c * 2 + (tb - 12)) * 512 + l * 8);
          gl_lds16(g, nb + tb * 1024);
        }
      }
    }
    // GEMM1: S^T[g32][b32], K=32 (scale pre-folded into E)
    bf16x8 aE0 = *(const bf16x8*)(cb + 12288 + l * 16);
    bf16x8 aE1 = *(const bf16x8*)(cb + 13312 + l * 16);
    f32x16 s = ZERO16;
    s = __builtin_amdgcn_mfma_f32_32x32x16_bf16(aE0, xf[0], s, 0, 0, 0);
    s = __builtin_amdgcn_mfma_f32_32x32x16_bf16(aE1, xf[1], s, 0, 0, 0);
    // relu + pack; registers ARE the A-frags (E g-permutation)
    unsigned int dw[8];
#pragma unroll
    for (int p = 0; p < 8; p++)
      dw[p] = pack_bf2f(fmaxf(s[2 * p], 0.f), fmaxf(s[2 * p + 1], 0.f));
    i32x4 q0 = (i32x4){(int)dw[0], (int)dw[1], (int)dw[2], (int)dw[3]};
    i32x4 q1 = (i32x4){(int)dw[4], (int)dw[5], (int)dw[6], (int)dw[7]};
    bf16x8 a20 = __builtin_bit_cast(bf16x8, q0);
    bf16x8 a21 = __builtin_bit_cast(bf16x8, q1);
    // GEMM2: this wave's 96-n half (3 chains x 2 k-tiles)
#pragma unroll
    for (int gk = 0; gk < 2; gk++) {
      bf16x8 a2 = gk ? a21 : a20;
#pragma unroll
      for (int nf = 0; nf < 3; nf++) {
        bf16x8 b2 = *(const bf16x8*)(cb + ((ng * 3 + nf) * 2 + gk) * 1024 + l * 16);
        o[nf] = __builtin_amdgcn_mfma_f32_32x32x16_bf16(a2, b2, o[nf], 0, 0, 0);
      }
    }
  }

  // store partials: part[((h*16+y)*2048 + b)*192 + n]   (32 slices = 25.2 MB)
  unsigned short* pp = part + (size_t)((h * 16 + y) * 2048 + bt * 32) * 192;
#pragma unroll
  for (int nf = 0; nf < 3; nf++) {
    int n = ng * 96 + nf * 32 + ln;
    if (n < 176) {
#pragma unroll
      for (int r = 0; r < 16; r++) {
        int row = (r & 3) + 8 * (r >> 2) + 4 * hl;
        pp[row * 192 + n] = f2bf(o[nf][r]);
      }
    }
  }
}

// ---------------- partial reduce (2 halves) + so3_to_so3 (psi2 in LDS) ----------------
__global__ __launch_bounds__(256) void so3_k(const unsigned short* __restrict__ part,
                                             const float* __restrict__ psi2,
                                             float* __restrict__ harm_out,
                                             unsigned short* __restrict__ harmbpre) {
  __shared__ float lds[4 * 16 * 180];
  __shared__ float p2s[2640];
  const int tid = threadIdx.x;
  const int b0 = blockIdx.x * 4;
  for (int e = tid; e < 2640; e += 256) p2s[e] = psi2[e];
  {
    const int ybl = tid >> 2;
    const int yy = ybl & 15, bloc = ybl >> 4;
    const int s = tid & 3;
    const unsigned int* r0 = (const unsigned int*)(part + ((size_t)(0 * 16 + yy) * 2048 + b0 + bloc) * 192);
    const unsigned int* r1 = (const unsigned int*)(part + ((size_t)(1 * 16 + yy) * 2048 + b0 + bloc) * 192);
    float* dst = lds + (bloc * 16 + yy) * 180;
#pragma unroll
    for (int t = 0; t < 22; t++) {
      int d = s * 22 + t;
      if (d < 88) {
        unsigned int u0 = r0[d], u1 = r1[d];
        int n0 = d * 2;
        dst[n0]     = bf2f((unsigned short)(u0 & 0xFFFF)) + bf2f((unsigned short)(u1 & 0xFFFF));
        dst[n0 + 1] = bf2f((unsigned short)(u0 >> 16))    + bf2f((unsigned short)(u1 >> 16));
      }
    }
  }
  __syncthreads();
  for (int jj = tid; jj < 768; jj += 256) {
    int e = (jj * 683) >> 17;              // jj / 192
    int i = jj - e * 192;
    int bb = b0 + e;
    unsigned short* hb = harmbpre + (((bb >> 5) * 12 + (i >> 4)) << 9)
                       + ((i >> 3) & 1) * 256 + (bb & 31) * 8 + (i & 7);
    if (i < 165) {
      const float* row0 = lds + e * (16 * 180);
      int lv, rel; decode_i(i, lv, rel);
      int d = 2 * lv + 1;
      int off = i - rel;
      int v = divq(rel, lv), m = rel - v * d;
      float s = 0.f;
      for (int ch = 0; ch < 16; ch++) {
        const float* rw = row0 + ch * 180 + off;
        const float* p2 = p2s + ch * 165 + off;
        for (int u = 0; u < d; u++) s += rw[u * d + m] * p2[u * d + v];
      }
      s *= 0.25f * rsqrtf((float)d);
      harm_out[bb * 165 + i] = s;
      *hb = f2bf(s);
    } else {
      *hb = 0;
    }
  }
}

// ---------------- eval GEMM + row-0 logits side copy ----------------
__global__ __launch_bounds__(64) void eval_k(
    const unsigned short* __restrict__ harmbpre,
    const unsigned short* __restrict__ ewpre,
    float* __restrict__ logits,
    float* __restrict__ logit0)
{
  const int l = threadIdx.x;
  const int hl = l >> 5, ln = l & 31;
  const int mt = blockIdx.y;
  const int n0 = blockIdx.x * 192;

  bf16x8 a[12];
  const short* ap = (const short*)harmbpre + mt * 6144 + l * 8;
#pragma unroll
  for (int kf = 0; kf < 12; kf++) a[kf] = *(const bf16x8*)(ap + kf * 512);

  f32x16 acc[6];
#pragma unroll
  for (int nf = 0; nf < 6; nf++) acc[nf] = ZERO16;

  const short* bp = (const short*)ewpre + (blockIdx.x * 6) * 6144 + l * 8;
#pragma unroll
  for (int kf = 0; kf < 12; kf++) {
#pragma unroll
    for (int nf = 0; nf < 6; nf++) {
      bf16x8 b = *(const bf16x8*)(bp + nf * 6144 + kf * 512);
      acc[nf] = __builtin_amdgcn_mfma_f32_32x32x16_bf16(a[kf], b, acc[nf], 0, 0, 0);
    }
  }
#pragma unroll
  for (int nf = 0; nf < 6; nf++) {
    const int col = n0 + nf * 32 + ln;
#pragma unroll
    for (int r = 0; r < 16; r++) {
      int row = (r & 3) + 8 * (r >> 2) + 4 * hl;
      logits[(mt * 32 + row) * 4608 + col] = acc[nf][r];
    }
  }
  if (mt == 0 && hl == 0) {
#pragma unroll
    for (int nf = 0; nf < 6; nf++) logit0[n0 + nf * 32 + ln] = acc[nf][0];
  }
}

// ---------------- fifth prob from logit0 (single block) ----------------
__global__ __launch_bounds__(256) void fifth_k(const float* __restrict__ logit0,
                                               float* __restrict__ fifth) {
  __shared__ float buf[4608];
  __shared__ float sm[4], ss[4];
  __shared__ float wv[4]; __shared__ int wi[4];
  __shared__ float gbest;
  const int tid = threadIdx.x;
  const int l = tid & 63, w = tid >> 6;
  float v[18];
  float mx = -3.4e38f;
#pragma unroll
  for (int i = 0; i < 18; i++) {
    v[i] = logit0[i * 256 + tid];
    buf[i * 256 + tid] = v[i];
    mx = fmaxf(mx, v[i]);
  }
#pragma unroll
  for (int off = 32; off >= 1; off >>= 1) mx = fmaxf(mx, __shfl_xor(mx, off));
  if (l == 0) sm[w] = mx;
  __syncthreads();
  mx = fmaxf(fmaxf(sm[0], sm[1]), fmaxf(sm[2], sm[3]));
  float s = 0.f;
#pragma unroll
  for (int i = 0; i < 18; i++) s += __expf(v[i] - mx);
#pragma unroll
  for (int off = 32; off >= 1; off >>= 1) s += __shfl_xor(s, off);
  if (l == 0) ss[w] = s;
  __syncthreads();
  s = ss[0] + ss[1] + ss[2] + ss[3];
  float inv = 1.f / s;

  float ff = 0.f;
  for (int it = 0; it < 5; it++) {
    float bm = -3.4e38f; int bi = 0;
    for (int i = tid; i < 4608; i += 256) {
      float xx = buf[i];
      if (xx > bm) { bm = xx; bi = i; }
    }
    for (int off = 32; off >= 1; off >>= 1) {
      float ov = __shfl_xor(bm, off); int oi = __shfl_xor(bi, off);
      if (ov > bm) { bm = ov; bi = oi; }
    }
    if (l == 0) { wv[w] = bm; wi[w] = bi; }
    __syncthreads();
    if (tid == 0) {
      float B = wv[0]; int I = wi[0];
      for (int k = 1; k < 4; k++) if (wv[k] > B) { B = wv[k]; I = wi[k]; }
      gbest = B;
      buf[I] = -3.4e38f;
    }
    __syncthreads();
    ff = gbest;
    __syncthreads();
  }
  if (tid == 0) *fifth = __expf(ff - mx) * inv;
}

// ---------------- fused softmax + threshold ----------------
__global__ __launch_bounds__(256) void smthresh_k(float* __restrict__ probs,
                                                  const float* __restrict__ fifth) {
  float* p = probs + (size_t)blockIdx.x * 4608;
  const int tid = threadIdx.x;
  const int l = tid & 63, w = tid >> 6;
  __shared__ float sm[4], ss[4];
  float v[18];
  float mx = -3.4e38f;
#pragma unroll
  for (int i = 0; i < 18; i++) { v[i] = p[i * 256 + tid]; mx = fmaxf(mx, v[i]); }
#pragma unroll
  for (int off = 32; off >= 1; off >>= 1) mx = fmaxf(mx, __shfl_xor(mx, off));
  if (l == 0) sm[w] = mx;
  __syncthreads();
  mx = fmaxf(fmaxf(sm[0], sm[1]), fmaxf(sm[2], sm[3]));
  float s = 0.f;
#pragma unroll
  for (int i = 0; i < 18; i++) { v[i] = __expf(v[i] - mx); s += v[i]; }
#pragma unroll
  for (int off = 32; off >= 1; off >>= 1) s += __shfl_xor(s, off);
  if (l == 0) ss[w] = s;
  __syncthreads();
  s = ss[0] + ss[1] + ss[2] + ss[3];
  float inv = 1.f / s;
  float t = *fifth;
#pragma unroll
  for (int i = 0; i < 18; i++) {
    float pv = v[i] * inv;
    p[i * 256 + tid] = (pv < t) ? 0.f : pv;
  }
}

extern "C" void kernel_launch(void* const* d_in, const int* in_sizes, int n_in,
                              void* d_out, int out_size, void* d_ws, size_t ws_size,
                              hipStream_t stream) {
  const float* x     = (const float*)d_in[0];
  const float* w_s2  = (const float*)d_in[1];
  const float* Y     = (const float*)d_in[2];
  const float* w_so3 = (const float*)d_in[3];
  const float* Dk    = (const float*)d_in[4];
  const float* Da    = (const float*)d_in[5];
  const float* ew    = (const float*)d_in[6];

  float* out = (float*)d_out;
  float* harm_out = out;                 // 2048*165
  float* probs    = out + 337920;        // 2048*4608 (partials -> logits -> probs)
  unsigned short* part = (unsigned short*)probs;   // 32 slices = 25.2 MB

  char* ws = (char*)d_ws;
  float* psi2  = (float*)(ws + 0);                         // 10,560 B
  float* fifth = (float*)(ws + 10560);                     // 4 B
  unsigned short* e1pre    = (unsigned short*)(ws + 12288);      // 4,194,304 B
  unsigned short* d2pre    = (unsigned short*)(ws + 4206592);    // 1,572,864 B
  unsigned short* ewpre    = (unsigned short*)(ws + 5779456);    // 1,769,472 B
  unsigned short* harmbpre = (unsigned short*)(ws + 7548928);    // 786,432 B
  float* logit0 = (float*)(ws + 8335360);                        // 18,432 B (~8.35 MB)

  prep_k<<<595, 256, 0, stream>>>(Da, ew, Y, w_s2, Dk, w_so3, e1pre, d2pre, ewpre, psi2);
  fused_mlp_k<<<1024, 256, 0, stream>>>(x, e1pre, d2pre, part);
  so3_k<<<512, 256, 0, stream>>>(part, psi2, harm_out, harmbpre);
  eval_k<<<dim3(24, 64), 64, 0, stream>>>(harmbpre, ewpre, probs, logit0);
  fifth_k<<<1, 256, 0, stream>>>(logit0, fifth);
  smthresh_k<<<2048, 256, 0, stream>>>(probs, fifth);
}

// Round 13
// 216.434 us; speedup vs baseline: 1.1022x; 1.1022x over previous
//
#include <hip/hip_runtime.h>

typedef short bf16x8 __attribute__((ext_vector_type(8)));
typedef float f32x16 __attribute__((ext_vector_type(16)));
typedef int   i32x4  __attribute__((ext_vector_type(4)));

#define INV_SQRT165 0.07784989441615349f
#define FINAL_SCALE 0.0032113081446662823f   /* sqrt(165)/4000 */
#define ZERO16 ((f32x16){0.f,0.f,0.f,0.f,0.f,0.f,0.f,0.f,0.f,0.f,0.f,0.f,0.f,0.f,0.f,0.f})

__device__ __forceinline__ unsigned short f2bf(float f) {
  unsigned int u = __builtin_bit_cast(unsigned int, f);
  unsigned int r = (u + 0x7FFFu + ((u >> 16) & 1u)) >> 16;
  return (unsigned short)r;
}
__device__ __forceinline__ float bf2f(unsigned short h) {
  unsigned int u = ((unsigned int)h) << 16;
  return __builtin_bit_cast(float, u);
}
// fast pack: round-half-up (2 ops/value); inputs are relu'd (>=0)
__device__ __forceinline__ unsigned int pack_bf2f(float lo, float hi) {
  unsigned int a = (__builtin_bit_cast(unsigned int, lo) + 0x8000u) >> 16;
  unsigned int b = (__builtin_bit_cast(unsigned int, hi) + 0x8000u) & 0xFFFF0000u;
  return b | a;
}

__device__ __forceinline__ void gl_lds16(const void* g, void* l) {
  __builtin_amdgcn_global_load_lds(
      (const __attribute__((address_space(1))) unsigned int*)(unsigned long long)g,
      (__attribute__((address_space(3))) unsigned int*)(unsigned int)(unsigned long long)l,
      16, 0, 0);
}

__device__ __forceinline__ void decode_i(int i, int& lv, int& rel) {
  if (i < 1)       { lv = 0; rel = i; }
  else if (i < 10) { lv = 1; rel = i - 1; }
  else if (i < 35) { lv = 2; rel = i - 10; }
  else if (i < 84) { lv = 3; rel = i - 35; }
  else             { lv = 4; rel = i - 84; }
}
__device__ __forceinline__ int divq(int rel, int lv) {   // rel / (2lv+1), rel < 81
  const int mag[5] = {32768, 10923, 6554, 4682, 3641};
  return (rel * mag[lv]) >> 15;
}

// E-row permutation: row p holds actual g = G(p) so GEMM1's C/D register order IS
// GEMM2's A-frag k-slot order (no cross-lane exchange).
__device__ __forceinline__ int gperm(int p) {
  int a = p & 3, hlp = (p >> 2) & 1, c = p >> 3;
  return ((c >> 1) << 4) + hlp * 8 + ((c & 1) << 2) + a;
}

// ---------------- prep ----------------
// blocks 0..511: (ci = bx>>2, yg = bx&3) Da chunk -> E-fold for 4 y; yg==0 also d2pre.
// blocks 512..583: ewpre. blocks 584..594: psi2.
__global__ __launch_bounds__(256) void prep_k(const float* __restrict__ Da,
                                              const float* __restrict__ ew,
                                              const float* __restrict__ Y,
                                              const float* __restrict__ w_s2,
                                              const float* __restrict__ Dk,
                                              const float* __restrict__ w_so3,
                                              unsigned short* __restrict__ e1pre,
                                              unsigned short* __restrict__ d2pre,
                                              unsigned short* __restrict__ ewpre,
                                              float* __restrict__ psi2) {
  __shared__ __align__(16) unsigned short lds[13824];
  const int tid = threadIdx.x;
  const int l = tid & 63, hl = l >> 5, ln = l & 31;
  if (blockIdx.x < 512) {
    const int ci = blockIdx.x >> 2, yg = blockIdx.x & 3;
    const int g0 = ci * 32;
    float* psi1L = (float*)(lds + 6464);
    for (int e = tid; e < 6400; e += 256) lds[e] = 0;
    for (int e = tid; e < 400; e += 256) {
      int yv = e / 25, iv = e % 25;
      float s = 0.f;
      for (int n = 0; n < 48; n++) s += Y[n * 25 + iv] * w_s2[yv * 48 + n];
      psi1L[e] = s * 0.14433756729740643f;
    }
    __syncthreads();
    int rows = 4000 - g0; if (rows > 32) rows = 32; if (rows < 0) rows = 0;
    int ne = rows * 165;
    for (int e = tid; e < ne; e += 256) {
      int gl_ = e / 165, k = e - gl_ * 165;
      lds[gl_ * 200 + k] = f2bf(Da[g0 * 165 + e]);
    }
    __syncthreads();
    if (yg == 0) {
#pragma unroll
      for (int it = 0; it < 3; it++) {
        int tt = it * 4 + (tid >> 6);
        int nf = tt >> 1, gk = tt & 1;
        unsigned short v[8];
#pragma unroll
        for (int j = 0; j < 8; j++)
          v[j] = lds[(gk * 16 + hl * 8 + j) * 200 + nf * 32 + ln];
        *(i32x4*)(d2pre + ci * 6144 + tt * 512 + l * 8) = *(i32x4*)v;
      }
    }
    for (int yi = 0; yi < 4; yi++) {
      int yy = yg * 4 + yi;
#pragma unroll
      for (int it = 0; it < 4; it++) {
        int idx = it * 256 + tid;
        int kf = idx >> 9, r2 = idx & 511;
        int ll = r2 >> 3, j = r2 & 7;
        int lnn = ll & 31, hll = ll >> 5;
        int k = kf * 16 + hll * 8 + j;
        unsigned short ov = 0;
        if (k < 25) {
          int lv = (k < 1) ? 0 : (k < 4) ? 1 : (k < 9) ? 2 : (k < 16) ? 3 : 4;
          int d = 2 * lv + 1;
          int m = k - lv * lv;
          int off165 = lv * (4 * lv * lv - 1) / 3;   // {0,1,10,35,84}
          int gp = gperm(lnn);
          float s = 0.f;
          const float* pr = psi1L + yy * 25 + lv * lv;
          const unsigned short* dr = lds + gp * 200 + off165 + m;
          for (int j2 = 0; j2 < d; j2++) s += pr[j2] * bf2f(dr[j2 * d]);
          ov = f2bf(s * INV_SQRT165);
        }
        e1pre[((yy * 128 + ci) * 2 + kf) * 512 + ll * 8 + j] = ov;
      }
    }
  } else if (blockIdx.x < 584) {
    const int bx2 = blockIdx.x - 512;
    const int n0 = bx2 * 64;
    for (int e = tid; e < 13824; e += 256) lds[e] = 0;
    __syncthreads();
    for (int e = tid; e < 10560; e += 256) {
      int k = e >> 6, n = e & 63;
      lds[k * 72 + n] = f2bf(ew[k * 4608 + n0 + n]);
    }
    __syncthreads();
#pragma unroll
    for (int it = 0; it < 6; it++) {
      int tb = it * 4 + (tid >> 6);
      int nt2 = tb / 12, kf = tb - nt2 * 12;
      unsigned short v[8];
#pragma unroll
      for (int j = 0; j < 8; j++)
        v[j] = lds[(kf * 16 + hl * 8 + j) * 72 + nt2 * 32 + ln];
      *(i32x4*)(ewpre + (bx2 * 2 + nt2) * 6144 + kf * 512 + l * 8) = *(i32x4*)v;
    }
  } else {
    int t = (blockIdx.x - 584) * 256 + tid;
    if (t < 2640) {
      int ch = t / 165, i = t % 165;
      float s = 0.f;
      for (int n = 0; n < 192; n++) s += Dk[n * 165 + i] * w_so3[ch * 192 + n];
      psi2[t] = s * (0.07216878364870323f * FINAL_SCALE);
    }
  }
}

// ---------------- fused MLP: permuted-E, R11 chain, E in register prefetch ----------------
// Grid 768: h = bx>>8 (g-third), y = (bx>>4)&15, btg = bx&15. Wave = 32b x 192n.
// E(ci+1) prefetched into REGISTERS via global loads issued with the d2 DMA; the
// pre-barrier vmcnt(0) drain guarantees readiness -> GEMM1 issues with zero wait
// post-barrier and overlaps the 12 B ds_reads. 12KB dbuf (24KB LDS), 3 blocks/CU.
__global__ __launch_bounds__(256, 3) void fused_mlp_k(
    const float* __restrict__ x,
    const unsigned short* __restrict__ e1pre,
    const unsigned short* __restrict__ d2pre,
    unsigned short* __restrict__ part)
{
  __shared__ __align__(16) unsigned char smem[24576];   // 2 x 12KB d2
  const int tid = threadIdx.x;
  const int w = tid >> 6, l = tid & 63;
  const int hl = l >> 5, ln = l & 31;
  const int h = blockIdx.x >> 8;                 // 0..2
  const int y = (blockIdx.x >> 4) & 15;
  const int btg = blockIdx.x & 15;
  const int bt = btg * 4 + w;
  const int c0 = (h == 0) ? 0 : (h == 1) ? 43 : 86;
  const int cnt = (h == 2) ? 42 : 43;

  // x fragments (B-operand of GEMM1): lane ln -> batch b = bt*32+ln, k pad to 32
  bf16x8 xf[2];
  {
    const float* xr = x + (bt * 32 + ln) * 25;
#pragma unroll
    for (int kf = 0; kf < 2; kf++) {
      unsigned short v[8];
#pragma unroll
      for (int j = 0; j < 8; j++) {
        int k = kf * 16 + hl * 8 + j;
        v[j] = (k < 25) ? f2bf(xr[k]) : (unsigned short)0;
      }
      xf[kf] = *(bf16x8*)v;
    }
  }

  f32x16 o[6];
#pragma unroll
  for (int i = 0; i < 6; i++) o[i] = ZERO16;

  const unsigned short* ebase = e1pre + (y * 128) * 1024;

  // E(c0) direct to registers; d2(c0) via DMA (12 x 1KB, 3 per wave)
  bf16x8 eC0 = *(const bf16x8*)(ebase + (c0 * 2 + 0) * 512 + l * 8);
  bf16x8 eC1 = *(const bf16x8*)(ebase + (c0 * 2 + 1) * 512 + l * 8);
#pragma unroll
  for (int i = 0; i < 3; i++) {
    int tb = w * 3 + i;
    gl_lds16(d2pre + c0 * 6144 + tb * 512 + l * 8, smem + tb * 1024);
  }

  for (int ci = 0; ci < cnt; ci++) {
    __syncthreads();
    const unsigned char* cb = smem + (ci & 1) * 12288;
    bf16x8 eN0 = eC0, eN1 = eC1;
    if (ci + 1 < cnt) {
      unsigned char* nb = smem + ((ci + 1) & 1) * 12288;
      const int c = c0 + ci + 1;
#pragma unroll
      for (int i = 0; i < 3; i++) {
        int tb = w * 3 + i;
        gl_lds16(d2pre + c * 6144 + tb * 512 + l * 8, nb + tb * 1024);
      }
      eN0 = *(const bf16x8*)(ebase + (c * 2 + 0) * 512 + l * 8);
      eN1 = *(const bf16x8*)(ebase + (c * 2 + 1) * 512 + l * 8);
    }
    // GEMM1: S^T[g32][b32], K=32; E from registers (prefetched last iter) -> no wait
    f32x16 s = ZERO16;
    s = __builtin_amdgcn_mfma_f32_32x32x16_bf16(eC0, xf[0], s, 0, 0, 0);
    s = __builtin_amdgcn_mfma_f32_32x32x16_bf16(eC1, xf[1], s, 0, 0, 0);
    // relu + pack; registers ARE the A-frags (E g-permutation)
    unsigned int dw[8];
#pragma unroll
    for (int p = 0; p < 8; p++)
      dw[p] = pack_bf2f(fmaxf(s[2 * p], 0.f), fmaxf(s[2 * p + 1], 0.f));
    i32x4 q0 = (i32x4){(int)dw[0], (int)dw[1], (int)dw[2], (int)dw[3]};
    i32x4 q1 = (i32x4){(int)dw[4], (int)dw[5], (int)dw[6], (int)dw[7]};
    bf16x8 a20 = __builtin_bit_cast(bf16x8, q0);
    bf16x8 a21 = __builtin_bit_cast(bf16x8, q1);
    // GEMM2: 6 independent chains x 2 k-tiles (B ds_reads overlap GEMM1/pack)
#pragma unroll
    for (int gk = 0; gk < 2; gk++) {
      bf16x8 a2 = gk ? a21 : a20;
#pragma unroll
      for (int nf = 0; nf < 6; nf++) {
        bf16x8 b2 = *(const bf16x8*)(cb + (nf * 2 + gk) * 1024 + l * 16);
        o[nf] = __builtin_amdgcn_mfma_f32_32x32x16_bf16(a2, b2, o[nf], 0, 0, 0);
      }
    }
    eC0 = eN0; eC1 = eN1;
  }

  // store partials: part[((h*16+y)*2048 + b)*192 + n]   (48 slices = 37.75 MB)
  unsigned short* pp = part + (size_t)((h * 16 + y) * 2048 + bt * 32) * 192;
#pragma unroll
  for (int nf = 0; nf < 6; nf++) {
    int n = nf * 32 + ln;
    if (n < 176) {
#pragma unroll
      for (int r = 0; r < 16; r++) {
        int row = (r & 3) + 8 * (r >> 2) + 4 * hl;
        pp[row * 192 + n] = f2bf(o[nf][r]);
      }
    }
  }
}

// ---------------- partial reduce (3 thirds) + so3_to_so3 (psi2 in LDS) ----------------
__global__ __launch_bounds__(256) void so3_k(const unsigned short* __restrict__ part,
                                             const float* __restrict__ psi2,
                                             float* __restrict__ harm_out,
                                             unsigned short* __restrict__ harmbpre) {
  __shared__ float lds[4 * 16 * 180];
  __shared__ float p2s[2640];
  const int tid = threadIdx.x;
  const int b0 = blockIdx.x * 4;
  for (int e = tid; e < 2640; e += 256) p2s[e] = psi2[e];
  {
    const int ybl = tid >> 2;
    const int yy = ybl & 15, bloc = ybl >> 4;
    const int s = tid & 3;
    const unsigned int* r0 = (const unsigned int*)(part + ((size_t)(0 * 16 + yy) * 2048 + b0 + bloc) * 192);
    const unsigned int* r1 = (const unsigned int*)(part + ((size_t)(1 * 16 + yy) * 2048 + b0 + bloc) * 192);
    const unsigned int* r2 = (const unsigned int*)(part + ((size_t)(2 * 16 + yy) * 2048 + b0 + bloc) * 192);
    float* dst = lds + (bloc * 16 + yy) * 180;
#pragma unroll
    for (int t = 0; t < 22; t++) {
      int d = s * 22 + t;
      if (d < 88) {
        unsigned int u0 = r0[d], u1 = r1[d], u2 = r2[d];
        int n0 = d * 2;
        dst[n0]     = bf2f((unsigned short)(u0 & 0xFFFF)) + bf2f((unsigned short)(u1 & 0xFFFF))
                    + bf2f((unsigned short)(u2 & 0xFFFF));
        dst[n0 + 1] = bf2f((unsigned short)(u0 >> 16)) + bf2f((unsigned short)(u1 >> 16))
                    + bf2f((unsigned short)(u2 >> 16));
      }
    }
  }
  __syncthreads();
  for (int jj = tid; jj < 768; jj += 256) {
    int e = (jj * 683) >> 17;              // jj / 192
    int i = jj - e * 192;
    int bb = b0 + e;
    unsigned short* hb = harmbpre + (((bb >> 5) * 12 + (i >> 4)) << 9)
                       + ((i >> 3) & 1) * 256 + (bb & 31) * 8 + (i & 7);
    if (i < 165) {
      const float* row0 = lds + e * (16 * 180);
      int lv, rel; decode_i(i, lv, rel);
      int d = 2 * lv + 1;
      int off = i - rel;
      int v = divq(rel, lv), m = rel - v * d;
      float s = 0.f;
      for (int ch = 0; ch < 16; ch++) {
        const float* rw = row0 + ch * 180 + off;
        const float* p2 = p2s + ch * 165 + off;
        for (int u = 0; u < d; u++) s += rw[u * d + m] * p2[u * d + v];
      }
      s *= 0.25f * rsqrtf((float)d);
      harm_out[bb * 165 + i] = s;
      *hb = f2bf(s);
    } else {
      *hb = 0;
    }
  }
}

// ---------------- eval GEMM + row-0 logits side copy ----------------
__global__ __launch_bounds__(64) void eval_k(
    const unsigned short* __restrict__ harmbpre,
    const unsigned short* __restrict__ ewpre,
    float* __restrict__ logits,
    float* __restrict__ logit0)
{
  const int l = threadIdx.x;
  const int hl = l >> 5, ln = l & 31;
  const int mt = blockIdx.y;
  const int n0 = blockIdx.x * 192;

  bf16x8 a[12];
  const short* ap = (const short*)harmbpre + mt * 6144 + l * 8;
#pragma unroll
  for (int kf = 0; kf < 12; kf++) a[kf] = *(const bf16x8*)(ap + kf * 512);

  f32x16 acc[6];
#pragma unroll
  for (int nf = 0; nf < 6; nf++) acc[nf] = ZERO16;

  const short* bp = (const short*)ewpre + (blockIdx.x * 6) * 6144 + l * 8;
#pragma unroll
  for (int kf = 0; kf < 12; kf++) {
#pragma unroll
    for (int nf = 0; nf < 6; nf++) {
      bf16x8 b = *(const bf16x8*)(bp + nf * 6144 + kf * 512);
      acc[nf] = __builtin_amdgcn_mfma_f32_32x32x16_bf16(a[kf], b, acc[nf], 0, 0, 0);
    }
  }
#pragma unroll
  for (int nf = 0; nf < 6; nf++) {
    const int col = n0 + nf * 32 + ln;
#pragma unroll
    for (int r = 0; r < 16; r++) {
      int row = (r & 3) + 8 * (r >> 2) + 4 * hl;
      logits[(mt * 32 + row) * 4608 + col] = acc[nf][r];
    }
  }
  if (mt == 0 && hl == 0) {
#pragma unroll
    for (int nf = 0; nf < 6; nf++) logit0[n0 + nf * 32 + ln] = acc[nf][0];
  }
}

// ---------------- fifth prob from logit0 (single block) ----------------
__global__ __launch_bounds__(256) void fifth_k(const float* __restrict__ logit0,
                                               float* __restrict__ fifth) {
  __shared__ float buf[4608];
  __shared__ float sm[4], ss[4];
  __shared__ float wv[4]; __shared__ int wi[4];
  __shared__ float gbest;
  const int tid = threadIdx.x;
  const int l = tid & 63, w = tid >> 6;
  float v[18];
  float mx = -3.4e38f;
#pragma unroll
  for (int i = 0; i < 18; i++) {
    v[i] = logit0[i * 256 + tid];
    buf[i * 256 + tid] = v[i];
    mx = fmaxf(mx, v[i]);
  }
#pragma unroll
  for (int off = 32; off >= 1; off >>= 1) mx = fmaxf(mx, __shfl_xor(mx, off));
  if (l == 0) sm[w] = mx;
  __syncthreads();
  mx = fmaxf(fmaxf(sm[0], sm[1]), fmaxf(sm[2], sm[3]));
  float s = 0.f;
#pragma unroll
  for (int i = 0; i < 18; i++) s += __expf(v[i] - mx);
#pragma unroll
  for (int off = 32; off >= 1; off >>= 1) s += __shfl_xor(s, off);
  if (l == 0) ss[w] = s;
  __syncthreads();
  s = ss[0] + ss[1] + ss[2] + ss[3];
  float inv = 1.f / s;

  float ff = 0.f;
  for (int it = 0; it < 5; it++) {
    float bm = -3.4e38f; int bi = 0;
    for (int i = tid; i < 4608; i += 256) {
      float xx = buf[i];
      if (xx > bm) { bm = xx; bi = i; }
    }
    for (int off = 32; off >= 1; off >>= 1) {
      float ov = __shfl_xor(bm, off); int oi = __shfl_xor(bi, off);
      if (ov > bm) { bm = ov; bi = oi; }
    }
    if (l == 0) { wv[w] = bm; wi[w] = bi; }
    __syncthreads();
    if (tid == 0) {
      float B = wv[0]; int I = wi[0];
      for (int k = 1; k < 4; k++) if (wv[k] > B) { B = wv[k]; I = wi[k]; }
      gbest = B;
      buf[I] = -3.4e38f;
    }
    __syncthreads();
    ff = gbest;
    __syncthreads();
  }
  if (tid == 0) *fifth = __expf(ff - mx) * inv;
}

// ---------------- fused softmax + threshold ----------------
__global__ __launch_bounds__(256) void smthresh_k(float* __restrict__ probs,
                                                  const float* __restrict__ fifth) {
  float* p = probs + (size_t)blockIdx.x * 4608;
  const int tid = threadIdx.x;
  const int l = tid & 63, w = tid >> 6;
  __shared__ float sm[4], ss[4];
  float v[18];
  float mx = -3.4e38f;
#pragma unroll
  for (int i = 0; i < 18; i++) { v[i] = p[i * 256 + tid]; mx = fmaxf(mx, v[i]); }
#pragma unroll
  for (int off = 32; off >= 1; off >>= 1) mx = fmaxf(mx, __shfl_xor(mx, off));
  if (l == 0) sm[w] = mx;
  __syncthreads();
  mx = fmaxf(fmaxf(sm[0], sm[1]), fmaxf(sm[2], sm[3]));
  float s = 0.f;
#pragma unroll
  for (int i = 0; i < 18; i++) { v[i] = __expf(v[i] - mx); s += v[i]; }
#pragma unroll
  for (int off = 32; off >= 1; off >>= 1) s += __shfl_xor(s, off);
  if (l == 0) ss[w] = s;
  __syncthreads();
  s = ss[0] + ss[1] + ss[2] + ss[3];
  float inv = 1.f / s;
  float t = *fifth;
#pragma unroll
  for (int i = 0; i < 18; i++) {
    float pv = v[i] * inv;
    p[i * 256 + tid] = (pv < t) ? 0.f : pv;
  }
}

extern "C" void kernel_launch(void* const* d_in, const int* in_sizes, int n_in,
                              void* d_out, int out_size, void* d_ws, size_t ws_size,
                              hipStream_t stream) {
  const float* x     = (const float*)d_in[0];
  const float* w_s2  = (const float*)d_in[1];
  const float* Y     = (const float*)d_in[2];
  const float* w_so3 = (const float*)d_in[3];
  const float* Dk    = (const float*)d_in[4];
  const float* Da    = (const float*)d_in[5];
  const float* ew    = (const float*)d_in[6];

  float* out = (float*)d_out;
  float* harm_out = out;                 // 2048*165
  float* probs    = out + 337920;        // 2048*4608 (partials -> logits -> probs)
  unsigned short* part = (unsigned short*)probs;   // 48 slices = 37.75 MB exactly

  char* ws = (char*)d_ws;
  float* psi2  = (float*)(ws + 0);                         // 10,560 B
  float* fifth = (float*)(ws + 10560);                     // 4 B
  unsigned short* e1pre    = (unsigned short*)(ws + 12288);      // 4,194,304 B
  unsigned short* d2pre    = (unsigned short*)(ws + 4206592);    // 1,572,864 B
  unsigned short* ewpre    = (unsigned short*)(ws + 5779456);    // 1,769,472 B
  unsigned short* harmbpre = (unsigned short*)(ws + 7548928);    // 786,432 B
  float* logit0 = (float*)(ws + 8335360);                        // 18,432 B (~8.35 MB)

  prep_k<<<595, 256, 0, stream>>>(Da, ew, Y, w_s2, Dk, w_so3, e1pre, d2pre, ewpre, psi2);
  fused_mlp_k<<<768, 256, 0, stream>>>(x, e1pre, d2pre, part);
  so3_k<<<512, 256, 0, stream>>>(part, psi2, harm_out, harmbpre);
  eval_k<<<dim3(24, 64), 64, 0, stream>>>(harmbpre, ewpre, probs, logit0);
  fifth_k<<<1, 256, 0, stream>>>(logit0, fifth);
  smthresh_k<<<2048, 256, 0, stream>>>(probs, fifth);
}